// Round 9
// baseline (81.701 us; speedup 1.0000x reference)
//
#include <hip/hip_runtime.h>
#include <hip/hip_bf16.h>

typedef __attribute__((ext_vector_type(8))) _Float16 half8;
typedef __attribute__((ext_vector_type(4))) _Float16 half4;
typedef __attribute__((ext_vector_type(4))) float f32x4;

#define MFMAH(a,b,c) __builtin_amdgcn_mfma_f32_16x16x32_f16(a,b,c,0,0,0)

#define LOG2_10K_64 0.2076205059304595f
#define INV2PI 0.15915494309189535f

#define SCHEDB __builtin_amdgcn_sched_barrier(0)
#define SBAR   __builtin_amdgcn_s_barrier()

__device__ __forceinline__ void gload_lds16(const void* g, void* l) {
  __builtin_amdgcn_global_load_lds((const __attribute__((address_space(1))) void*)g,
                                   (__attribute__((address_space(3))) void*)l,
                                   16, 0, 0);
}

// ---------------------------------------------------------------------------
// Prep: W1 (2048x128 f32) -> W1t[n][k] f16; Wq/Wk/Wv -> transposed f16.
// ---------------------------------------------------------------------------
__global__ __launch_bounds__(256) void k_prep(const float* __restrict__ W1,
                                              const float* __restrict__ Wq,
                                              const float* __restrict__ Wk,
                                              const float* __restrict__ Wv,
                                              _Float16* __restrict__ W1t,
                                              _Float16* __restrict__ Wqkvt) {
  const int bid = blockIdx.x, tid = threadIdx.x;
  if (bid < 64) {
    __shared__ float Tl[64][65];
    const int kt0 = (bid >> 1) * 64, nt0 = (bid & 1) * 64;
    const int row = tid >> 2, c0 = (tid & 3) * 16;
#pragma unroll
    for (int e = 0; e < 16; e += 4) {
      float4 f = *(const float4*)(W1 + (size_t)(kt0 + row) * 128 + nt0 + c0 + e);
      Tl[row][c0 + e] = f.x; Tl[row][c0 + e + 1] = f.y;
      Tl[row][c0 + e + 2] = f.z; Tl[row][c0 + e + 3] = f.w;
    }
    __syncthreads();
    const int nrow = tid >> 2, kc0 = (tid & 3) * 16;
    _Float16* wp = W1t + (size_t)(nt0 + nrow) * 2048 + kt0 + kc0;
#pragma unroll
    for (int e = 0; e < 16; ++e) wp[e] = (_Float16)Tl[kc0 + e][nrow];
  } else {
    int r = (bid - 64) * 256 + tid;
    if (r < 3 * 16384) {
      int m = r >> 14, e = r & 16383;
      int n = e >> 7, k = e & 127;
      const float* W = (m == 0) ? Wq : (m == 1) ? Wk : Wv;
      Wqkvt[r] = (_Float16)W[k * 128 + n];
    }
  }
}

// ---------------------------------------------------------------------------
// PW1[s][n] = sum_k P[s][k] * W1[k][n]  (P analytic sin/cos), f32 out.
// 128 blocks x 256 thr; wave wv -> cols wv*32..+31 (2 tiles); K=2048 by MFMA.
// ---------------------------------------------------------------------------
__global__ __launch_bounds__(256) void k_pw1(const _Float16* __restrict__ W1t,
                                             float* __restrict__ PW1) {
  const int tid = threadIdx.x, lane = tid & 63, wv = tid >> 6;
  const int fr = lane & 15, hi = lane >> 4;
  const int s0 = blockIdx.x * 16;
  const float sf = (float)(s0 + fr);
  const _Float16* bp0 = W1t + (size_t)(wv * 32 + fr) * 2048 + hi * 8;
  const _Float16* bp1 = W1t + (size_t)(wv * 32 + 16 + fr) * 2048 + hi * 8;
  f32x4 acc0 = {}, acc1 = {};
#pragma unroll 1
  for (int ks = 0; ks < 64; ++ks) {
    const int kb = ks * 32 + hi * 8;
    half8 a;
#pragma unroll
    for (int p = 0; p < 4; ++p) {
      const int jh = (kb >> 1) + p;
      float cc = exp2f((float)jh * -LOG2_10K_64) * INV2PI;
      float rr = __builtin_fmaf(sf, cc, -rintf(sf * cc));
      a[2 * p]     = (_Float16)__builtin_amdgcn_sinf(rr);
      a[2 * p + 1] = (_Float16)__builtin_amdgcn_cosf(rr);
    }
    half8 b0  = *(const half8*)(bp0 + ks * 32);
    half8 b1v = *(const half8*)(bp1 + ks * 32);
    acc0 = MFMAH(a, b0, acc0);
    acc1 = MFMAH(a, b1v, acc1);
  }
#pragma unroll
  for (int r = 0; r < 4; ++r) {
    const int row = s0 + hi * 4 + r;
    PW1[(size_t)row * 128 + wv * 32 + fr]      = acc0[r];
    PW1[(size_t)row * 128 + wv * 32 + 16 + fr] = acc1[r];
  }
}

// ---------------------------------------------------------------------------
// Fused GEMM1 + QKV with depth-3 counted-vmcnt pipeline (raw s_barrier; the
// main loop NEVER drains vmcnt to 0). h = relu(x@W1 + PW1[s] + b1);
// {Q,K,V} = h@{Wq,Wk,Wv}. BM=16, chunk = 256 k (16 KB fp32 in LDS, x only).
// 8 waves; wave wv owns output cols wv*16..+15 and stages rows 2wv,2wv+1
// (exactly 2 gload_lds per chunk -> countable vmcnt). Source-side XOR
// swizzle (16B-unit ^ (row&7)<<1) + matching read XOR: <=2-way conflicts.
// Grid 512, 512 thr, LDS 48 KB -> 2 blocks/CU.
// ---------------------------------------------------------------------------
__global__ __launch_bounds__(512) void k_fused(const float* __restrict__ x,
                                               const _Float16* __restrict__ W1t,
                                               const float* __restrict__ PW1,
                                               const _Float16* __restrict__ Wqkv,
                                               const float* __restrict__ b1,
                                               _Float16* __restrict__ Qg,
                                               _Float16* __restrict__ Kg,
                                               _Float16* __restrict__ Vg) {
  __shared__ __align__(16) char smem[49152];   // 3 x 16 KB chunk buffers
  const int tid = threadIdx.x;
  const int lane = tid & 63, wv = tid >> 6;
  const int fr = lane & 15, hi = lane >> 4;
  const int sw = fr & 7;
  const int i0 = blockIdx.x * 16;

  // staging: wave wv owns rows 2wv, 2wv+1; per-lane pre-swizzled source
  const int r0 = 2 * wv, r1 = 2 * wv + 1;
  const float* xsrc0 = x + (size_t)(i0 + r0) * 2048 + (lane ^ ((r0 & 7) << 1)) * 4;
  const float* xsrc1 = x + (size_t)(i0 + r1) * 2048 + (lane ^ ((r1 & 7) << 1)) * 4;
  const _Float16* brow = W1t + (size_t)(wv * 16 + fr) * 2048 + hi * 8;

  auto stage = [&](int buf, int c) {
    gload_lds16(xsrc0 + c * 256, smem + buf * 16384 + r0 * 1024);
    gload_lds16(xsrc1 + c * 256, smem + buf * 16384 + r1 * 1024);
  };

  f32x4 acc = {};
  auto compute = [&](int buf, int c) {
    const char* axc = smem + buf * 16384 + fr * 1024;
    const _Float16* bp = brow + c * 256;
#pragma unroll
    for (int ks = 0; ks < 8; ++ks) {
      const int u = ((ks * 4 + hi) ^ sw) * 32;
      f32x4 x0 = *(const f32x4*)(axc + u);
      f32x4 x1 = *(const f32x4*)(axc + u + 16);
      half8 af;
#pragma unroll
      for (int e = 0; e < 4; ++e) af[e] = (_Float16)x0[e];
#pragma unroll
      for (int e = 0; e < 4; ++e) af[4 + e] = (_Float16)x1[e];
      half8 b = *(const half8*)(bp + ks * 32);
      acc = MFMAH(af, b, acc);
    }
  };

  // prologue: 3 chunks in flight (6 gload_lds per wave)
  stage(0, 0); stage(1, 1); stage(2, 2);

#pragma unroll 1
  for (int c = 0; c < 6; ++c) {
    SCHEDB;
    asm volatile("s_waitcnt vmcnt(4)" ::: "memory");   // chunk c landed
    SCHEDB;
    SBAR;                                              // all waves' rows landed
    SCHEDB;
    compute(c % 3, c);
    SBAR;                                              // all reads of buf done
    SCHEDB;
    if (c < 5) stage(c % 3, c + 3);                    // (c+3)%3 == c%3
  }
  // c = 6: only chunks 6,7 outstanding (4 ops)
  SCHEDB;
  asm volatile("s_waitcnt vmcnt(2)" ::: "memory");
  SCHEDB; SBAR; SCHEDB;
  compute(0, 6);
  SBAR; SCHEDB;
  // c = 7
  asm volatile("s_waitcnt vmcnt(0)" ::: "memory");
  SCHEDB; SBAR; SCHEDB;
  compute(1, 7);

  // epilogue: h = relu(acc + PW1[s] + b1) -> Hs f16 (overlay buf0), then QKV
  __syncthreads();
  _Float16 (*Hs)[136] = (_Float16(*)[136])smem;
  {
    const int col = wv * 16 + fr;
    const float bv = b1[col];
#pragma unroll
    for (int r = 0; r < 4; ++r) {
      const int row = i0 + hi * 4 + r;
      float v = acc[r] + PW1[(size_t)(row & 2047) * 128 + col] + bv;
      v = v > 0.f ? v : 0.f;
      Hs[hi * 4 + r][col] = (_Float16)v;
    }
  }
  __syncthreads();
  const _Float16* wqrow = Wqkv + (size_t)(wv * 16 + fr) * 128 + hi * 8;
#pragma unroll 1
  for (int m = 0; m < 3; ++m) {
    f32x4 a2 = {};
#pragma unroll
    for (int kk = 0; kk < 4; ++kk) {
      half8 a = *(const half8*)&Hs[fr][kk * 32 + hi * 8];
      half8 b = *(const half8*)(wqrow + m * 16384 + kk * 32);
      a2 = MFMAH(a, b, a2);
    }
    _Float16* dst = (m == 0) ? Qg : (m == 1) ? Kg : Vg;
#pragma unroll
    for (int r = 0; r < 4; ++r)
      dst[(size_t)(i0 + hi * 4 + r) * 128 + wv * 16 + fr] = (_Float16)a2[r];
  }
}

// ---------------------------------------------------------------------------
// Attention via MFMA. Block = 16 q-rows of one batch; 4 waves; grid 512.
// Zero K-rows outside sequence -> score 0 (included), matching reference.
// ---------------------------------------------------------------------------
__global__ __launch_bounds__(256) void k_attn(const _Float16* __restrict__ Qg,
                                              const _Float16* __restrict__ Kg,
                                              const _Float16* __restrict__ Vg,
                                              const float* __restrict__ Wo,
                                              const float* __restrict__ bo,
                                              float* __restrict__ outp,
                                              float* __restrict__ attwg) {
  __shared__ _Float16 Qs[16][136];
  __shared__ _Float16 Ks[80][136];
  __shared__ _Float16 Vs[96][136];
  __shared__ _Float16 Ps[16][104];
  __shared__ float sc[16][84];
  __shared__ float aw[16 * 65];
  __shared__ float wol[128][2];
  __shared__ float proj[4][16][2];
  const int tid = threadIdx.x;
  const int lane = tid & 63, wv = tid >> 6;
  const int b = blockIdx.x >> 7;
  const int i0 = (blockIdx.x & 127) << 4;
  const int rowbase = b * 2048 + i0;
  const float invscale = 0.08838834764831845f;  // 1/sqrt(128)

  {
    const int row = tid >> 4, d8 = (tid & 15) * 8;
    *(half8*)&Qs[row][d8] = *(const half8*)(Qg + (size_t)(rowbase + row) * 128 + d8);
  }
#pragma unroll
  for (int it = 0; it < 5; ++it) {
    const int idx = it * 256 + tid;
    const int lr = idx >> 4, d8 = (idx & 15) * 8;
    const int j = i0 - 32 + lr;
    half8 kv = {0, 0, 0, 0, 0, 0, 0, 0};
    if (j >= 0 && j < 2048)
      kv = *(const half8*)(Kg + (size_t)(b * 2048 + j) * 128 + d8);
    *(half8*)&Ks[lr][d8] = kv;
  }
#pragma unroll
  for (int it = 0; it < 6; ++it) {
    const int idx = it * 256 + tid;
    const int lr = idx >> 4, d8 = (idx & 15) * 8;
    const int j = i0 - 32 + lr;
    half8 vv = {0, 0, 0, 0, 0, 0, 0, 0};
    if (lr < 80 && j >= 0 && j < 2048)
      vv = *(const half8*)(Vg + (size_t)(b * 2048 + j) * 128 + d8);
    *(half8*)&Vs[lr][d8] = vv;
  }
  wol[tid >> 1][tid & 1] = Wo[tid];
  __syncthreads();

  const int fr = lane & 15, kg8 = (lane >> 4) * 8;
  // QK^T: C[16 q][80 k] = 5 col-tiles
  {
    const int nct = (wv == 0) ? 2 : 1;
    for (int p = 0; p < nct; ++p) {
      const int ct = (p == 0) ? wv : 4;
      f32x4 acc = {};
#pragma unroll
      for (int kk = 0; kk < 4; ++kk) {
        half8 a  = *(const half8*)&Qs[fr][kk * 32 + kg8];
        half8 bb = *(const half8*)&Ks[ct * 16 + fr][kk * 32 + kg8];
        acc = MFMAH(a, bb, acc);
      }
#pragma unroll
      for (int r = 0; r < 4; ++r)
        sc[(lane >> 4) * 4 + r][ct * 16 + fr] = acc[r] * invscale;
    }
  }
  __syncthreads();

  // banded softmax; wave wv owns q-rows 4wv..4wv+3
#pragma unroll 1
  for (int rr = 0; rr < 4; ++rr) {
    const int r = wv * 4 + rr;
    const int c0 = lane;
    const bool ib0 = (c0 >= r);
    const bool ib1 = (lane <= r);
    float a0 = ib0 ? sc[r][c0] : -1e30f;
    float a1 = ib1 ? sc[r][64 + lane] : -1e30f;
    float mx = fmaxf(a0, a1);
#pragma unroll
    for (int o = 1; o < 64; o <<= 1) mx = fmaxf(mx, __shfl_xor(mx, o));
    float e0 = ib0 ? __expf(a0 - mx) : 0.f;
    float e1 = ib1 ? __expf(a1 - mx) : 0.f;
    float sm = e0 + e1;
#pragma unroll
    for (int o = 1; o < 64; o <<= 1) sm += __shfl_xor(sm, o);
    const float inv = 1.0f / sm;
    const float w0 = e0 * inv, w1 = e1 * inv;
    if (ib0) aw[r * 65 + (r + 64 - c0)] = w0;
    if (ib1) aw[r * 65 + (r - lane)] = w1;
    Ps[r][c0] = (_Float16)w0;
    if (lane < 32) Ps[r][64 + lane] = (_Float16)((lane < 16) ? w1 : 0.f);
  }
  __syncthreads();

  for (int i = tid; i < 1040; i += 256)
    attwg[(size_t)rowbase * 65 + i] = aw[i];

  // PV: C2[16 q][128 d] = P(16x96) @ V(96x128)
  f32x4 c2[2] = {};
#pragma unroll
  for (int kk = 0; kk < 3; ++kk) {
    half8 a = *(const half8*)&Ps[fr][kk * 32 + kg8];
#pragma unroll
    for (int dt2 = 0; dt2 < 2; ++dt2) {
      const int d = (2 * wv + dt2) * 16 + fr;
      half8 bb;
#pragma unroll
      for (int e = 0; e < 8; ++e) bb[e] = Vs[kk * 32 + kg8 + e][d];
      c2[dt2] = MFMAH(a, bb, c2[dt2]);
    }
  }
  // projection
#pragma unroll
  for (int r = 0; r < 4; ++r) {
    float p0 = 0.f, p1 = 0.f;
#pragma unroll
    for (int dt2 = 0; dt2 < 2; ++dt2) {
      const int d = (2 * wv + dt2) * 16 + fr;
      p0 += c2[dt2][r] * wol[d][0];
      p1 += c2[dt2][r] * wol[d][1];
    }
    p0 += __shfl_xor(p0, 1); p0 += __shfl_xor(p0, 2);
    p0 += __shfl_xor(p0, 4); p0 += __shfl_xor(p0, 8);
    p1 += __shfl_xor(p1, 1); p1 += __shfl_xor(p1, 2);
    p1 += __shfl_xor(p1, 4); p1 += __shfl_xor(p1, 8);
    if (fr == 0) {
      const int q = (lane >> 4) * 4 + r;
      proj[wv][q][0] = p0;
      proj[wv][q][1] = p1;
    }
  }
  __syncthreads();
  if (tid < 16) {
    float s0 = proj[0][tid][0] + proj[1][tid][0] + proj[2][tid][0] + proj[3][tid][0];
    float s1 = proj[0][tid][1] + proj[1][tid][1] + proj[2][tid][1] + proj[3][tid][1];
    outp[((size_t)rowbase + tid) * 2 + 0] = s0 * invscale + bo[0];
    outp[((size_t)rowbase + tid) * 2 + 1] = s1 * invscale + bo[1];
  }
}

extern "C" void kernel_launch(void* const* d_in, const int* in_sizes, int n_in,
                              void* d_out, int out_size, void* d_ws, size_t ws_size,
                              hipStream_t stream) {
  const float* x  = (const float*)d_in[0];
  const float* W1 = (const float*)d_in[1];
  const float* b1 = (const float*)d_in[2];
  const float* Wq = (const float*)d_in[3];
  const float* Wk = (const float*)d_in[4];
  const float* Wv = (const float*)d_in[5];
  const float* Wo = (const float*)d_in[6];
  const float* bo = (const float*)d_in[7];
  float* out  = (float*)d_out;            // (4,2048,2)
  float* attw = out + 16384;              // (4,2048,65)

  _Float16* W1t  = (_Float16*)d_ws;       // 128x2048
  _Float16* Wqkv = W1t + 262144;          // 3 x 128x128
  float*    PW1  = (float*)(Wqkv + 49152);// 2048x128 f32
  _Float16* Qg   = (_Float16*)(PW1 + 262144);  // 8192x128
  _Float16* Kg   = Qg + 1048576;
  _Float16* Vg   = Kg + 1048576;

  k_prep<<<256, 256, 0, stream>>>(W1, Wq, Wk, Wv, W1t, Wqkv);
  k_pw1<<<128, 256, 0, stream>>>(W1t, PW1);
  k_fused<<<512, 512, 0, stream>>>(x, W1t, PW1, Wqkv, b1, Qg, Kg, Vg);
  k_attn<<<512, 256, 0, stream>>>(Qg, Kg, Vg, Wo, bo, out, attw);
}

// Round 10
// 68.458 us; speedup vs baseline: 1.1934x; 1.1934x over previous
//
#include <hip/hip_runtime.h>
#include <hip/hip_bf16.h>

typedef __attribute__((ext_vector_type(8))) _Float16 half8;
typedef __attribute__((ext_vector_type(4))) _Float16 half4;
typedef __attribute__((ext_vector_type(4))) float f32x4;

#define MFMAH(a,b,c) __builtin_amdgcn_mfma_f32_16x16x32_f16(a,b,c,0,0,0)

#define LOG2_10K_64 0.2076205059304595f
#define INV2PI 0.15915494309189535f

// ---------------------------------------------------------------------------
// Prep: W1 (2048x128 f32) -> W1t[n][k] f16; Wq/Wk/Wv -> transposed f16.
// ---------------------------------------------------------------------------
__global__ __launch_bounds__(256) void k_prep(const float* __restrict__ W1,
                                              const float* __restrict__ Wq,
                                              const float* __restrict__ Wk,
                                              const float* __restrict__ Wv,
                                              _Float16* __restrict__ W1t,
                                              _Float16* __restrict__ Wqkvt) {
  const int bid = blockIdx.x, tid = threadIdx.x;
  if (bid < 64) {
    __shared__ float Tl[64][65];
    const int kt0 = (bid >> 1) * 64, nt0 = (bid & 1) * 64;
    const int row = tid >> 2, c0 = (tid & 3) * 16;
#pragma unroll
    for (int e = 0; e < 16; e += 4) {
      float4 f = *(const float4*)(W1 + (size_t)(kt0 + row) * 128 + nt0 + c0 + e);
      Tl[row][c0 + e] = f.x; Tl[row][c0 + e + 1] = f.y;
      Tl[row][c0 + e + 2] = f.z; Tl[row][c0 + e + 3] = f.w;
    }
    __syncthreads();
    const int nrow = tid >> 2, kc0 = (tid & 3) * 16;
    _Float16* wp = W1t + (size_t)(nt0 + nrow) * 2048 + kt0 + kc0;
#pragma unroll
    for (int e = 0; e < 16; ++e) wp[e] = (_Float16)Tl[kc0 + e][nrow];
  } else {
    int r = (bid - 64) * 256 + tid;
    if (r < 3 * 16384) {
      int m = r >> 14, e = r & 16383;
      int n = e >> 7, k = e & 127;
      const float* W = (m == 0) ? Wq : (m == 1) ? Wk : Wv;
      Wqkvt[r] = (_Float16)W[k * 128 + n];
    }
  }
}

// ---------------------------------------------------------------------------
// PW1[s][n] = sum_k P[s][k] * W1[k][n]  (P analytic sin/cos), f32 out.
// ---------------------------------------------------------------------------
__global__ __launch_bounds__(256) void k_pw1(const _Float16* __restrict__ W1t,
                                             float* __restrict__ PW1) {
  const int tid = threadIdx.x, lane = tid & 63, wv = tid >> 6;
  const int fr = lane & 15, hi = lane >> 4;
  const int s0 = blockIdx.x * 16;
  const float sf = (float)(s0 + fr);
  const _Float16* bp0 = W1t + (size_t)(wv * 32 + fr) * 2048 + hi * 8;
  const _Float16* bp1 = W1t + (size_t)(wv * 32 + 16 + fr) * 2048 + hi * 8;
  f32x4 acc0 = {}, acc1 = {};
#pragma unroll 1
  for (int ks = 0; ks < 64; ++ks) {
    const int kb = ks * 32 + hi * 8;
    half8 a;
#pragma unroll
    for (int p = 0; p < 4; ++p) {
      const int jh = (kb >> 1) + p;
      float cc = exp2f((float)jh * -LOG2_10K_64) * INV2PI;
      float rr = __builtin_fmaf(sf, cc, -rintf(sf * cc));
      a[2 * p]     = (_Float16)__builtin_amdgcn_sinf(rr);
      a[2 * p + 1] = (_Float16)__builtin_amdgcn_cosf(rr);
    }
    half8 b0  = *(const half8*)(bp0 + ks * 32);
    half8 b1v = *(const half8*)(bp1 + ks * 32);
    acc0 = MFMAH(a, b0, acc0);
    acc1 = MFMAH(a, b1v, acc1);
  }
#pragma unroll
  for (int r = 0; r < 4; ++r) {
    const int row = s0 + hi * 4 + r;
    PW1[(size_t)row * 128 + wv * 32 + fr]      = acc0[r];
    PW1[(size_t)row * 128 + wv * 32 + 16 + fr] = acc1[r];
  }
}

// ---------------------------------------------------------------------------
// GEMM1, 128x128 tile, BK=64, split-K=8: Hpart[ksp] = x[.,k-range] @ W1t^T.
// Grid 512 = 64 M-tiles x 8 K-splits; 512 thr = 8 waves (2 wr x 4 wc), each
// wave owns a 64x32 output quadrant = 4x2 independent accumulators (8-way
// MFMA ILP, 6 ds_read per 16 MFMAs). A staged fp32->f16 by VGPR (cvt once
// per element), B (f16 W1t, L2-hot) staged by VGPR; both into +8-half
// padded LDS (2-way conflicts = free). 2 barriers/step, 4 steps. 36 KB LDS.
// ---------------------------------------------------------------------------
__global__ __launch_bounds__(512) void k_gemm1(const float* __restrict__ x,
                                               const _Float16* __restrict__ W1t,
                                               float* __restrict__ Hpart) {
  __shared__ _Float16 Al[128][72];
  __shared__ _Float16 Bl[128][72];
  const int tid = threadIdx.x;
  const int lane = tid & 63, wv = tid >> 6;
  const int fr = lane & 15, hi = lane >> 4;
  const int mt = blockIdx.x >> 3, ksp = blockIdx.x & 7;
  const int i0 = mt * 128, k0 = ksp * 256;
  const int srow = tid >> 2, scol = (tid & 3) * 16;
  const float*    xp = x   + (size_t)(i0 + srow) * 2048 + k0 + scol;
  const _Float16* bp = W1t + (size_t)srow * 2048 + k0 + scol;
  const int wr = wv >> 2, wc = wv & 3;

  float4 xa0, xa1, xa2, xa3;
  half8 bb0, bb1;
  auto loads = [&](int s) {
    const float* p = xp + s * 64;
    xa0 = *(const float4*)p;       xa1 = *(const float4*)(p + 4);
    xa2 = *(const float4*)(p + 8); xa3 = *(const float4*)(p + 12);
    const _Float16* q = bp + s * 64;
    bb0 = *(const half8*)q;        bb1 = *(const half8*)(q + 8);
  };
  auto writes = [&]() {
    half8 h0, h1;
    h0[0] = (_Float16)xa0.x; h0[1] = (_Float16)xa0.y;
    h0[2] = (_Float16)xa0.z; h0[3] = (_Float16)xa0.w;
    h0[4] = (_Float16)xa1.x; h0[5] = (_Float16)xa1.y;
    h0[6] = (_Float16)xa1.z; h0[7] = (_Float16)xa1.w;
    h1[0] = (_Float16)xa2.x; h1[1] = (_Float16)xa2.y;
    h1[2] = (_Float16)xa2.z; h1[3] = (_Float16)xa2.w;
    h1[4] = (_Float16)xa3.x; h1[5] = (_Float16)xa3.y;
    h1[6] = (_Float16)xa3.z; h1[7] = (_Float16)xa3.w;
    *(half8*)&Al[srow][scol]     = h0;
    *(half8*)&Al[srow][scol + 8] = h1;
    *(half8*)&Bl[srow][scol]     = bb0;
    *(half8*)&Bl[srow][scol + 8] = bb1;
  };

  f32x4 acc[4][2] = {};
  loads(0);
#pragma unroll 1
  for (int s = 0; s < 4; ++s) {
    writes();
    __syncthreads();
    if (s < 3) loads(s + 1);
#pragma unroll
    for (int kk = 0; kk < 2; ++kk) {
      half8 af[4], bf[2];
#pragma unroll
      for (int mi = 0; mi < 4; ++mi)
        af[mi] = *(const half8*)&Al[wr * 64 + mi * 16 + fr][kk * 32 + hi * 8];
#pragma unroll
      for (int ni = 0; ni < 2; ++ni)
        bf[ni] = *(const half8*)&Bl[wc * 32 + ni * 16 + fr][kk * 32 + hi * 8];
#pragma unroll
      for (int mi = 0; mi < 4; ++mi)
#pragma unroll
        for (int ni = 0; ni < 2; ++ni)
          acc[mi][ni] = MFMAH(af[mi], bf[ni], acc[mi][ni]);
    }
    __syncthreads();
  }
  float* hp = Hpart + (size_t)ksp * 1048576;
#pragma unroll
  for (int mi = 0; mi < 4; ++mi)
#pragma unroll
    for (int ni = 0; ni < 2; ++ni)
#pragma unroll
      for (int r = 0; r < 4; ++r)
        hp[(size_t)(i0 + wr * 64 + mi * 16 + hi * 4 + r) * 128 +
           wc * 32 + ni * 16 + fr] = acc[mi][ni][r];
}

// ---------------------------------------------------------------------------
// Reduce 8 K-split partials + PW1 + b1, relu -> h (f16, LDS); QKV = h@{Wq,
// Wk,Wv} via MFMA (B direct from transposed Wqkv, L2-hot). 16 rows/block.
// ---------------------------------------------------------------------------
__global__ __launch_bounds__(256) void k_hqkv(const float* __restrict__ Hpart,
                                              const float* __restrict__ PW1,
                                              const float* __restrict__ b1,
                                              const _Float16* __restrict__ Wqkv,
                                              _Float16* __restrict__ Qg,
                                              _Float16* __restrict__ Kg,
                                              _Float16* __restrict__ Vg) {
  __shared__ _Float16 Hs[16][136];
  const int tid = threadIdx.x;
  const int lane = tid & 63, wv = tid >> 6;
  const int fr = lane & 15, hi = lane >> 4;
  const int i0 = blockIdx.x * 16;
  {
    const int row = tid >> 4, col = (tid & 15) * 8;
    const size_t base = (size_t)(i0 + row) * 128 + col;
    f32x4 s0 = {}, s1 = {};
#pragma unroll
    for (int p = 0; p < 8; ++p) {
      const float* pp = Hpart + (size_t)p * 1048576 + base;
      f32x4 a0 = *(const f32x4*)pp, a1 = *(const f32x4*)(pp + 4);
#pragma unroll
      for (int e = 0; e < 4; ++e) { s0[e] += a0[e]; s1[e] += a1[e]; }
    }
    const int srow = (i0 + row) & 2047;
    const float* pw = PW1 + (size_t)srow * 128 + col;
    half8 hv;
#pragma unroll
    for (int e = 0; e < 4; ++e) {
      float v0 = s0[e] + pw[e] + b1[col + e];
      float v1 = s1[e] + pw[4 + e] + b1[col + 4 + e];
      hv[e]     = (_Float16)(v0 > 0.f ? v0 : 0.f);
      hv[4 + e] = (_Float16)(v1 > 0.f ? v1 : 0.f);
    }
    *(half8*)&Hs[row][col] = hv;
  }
  __syncthreads();
  // QKV: wave wv owns cols wv*32..+31 of each output
#pragma unroll 1
  for (int m = 0; m < 3; ++m) {
    f32x4 a2[2] = {};
#pragma unroll
    for (int kk = 0; kk < 4; ++kk) {
      half8 a = *(const half8*)&Hs[fr][kk * 32 + hi * 8];
#pragma unroll
      for (int ni = 0; ni < 2; ++ni) {
        half8 b = *(const half8*)(Wqkv + (size_t)m * 16384 +
                                  (size_t)(wv * 32 + ni * 16 + fr) * 128 +
                                  kk * 32 + hi * 8);
        a2[ni] = MFMAH(a, b, a2[ni]);
      }
    }
    _Float16* dst = (m == 0) ? Qg : (m == 1) ? Kg : Vg;
#pragma unroll
    for (int ni = 0; ni < 2; ++ni)
#pragma unroll
      for (int r = 0; r < 4; ++r)
        dst[(size_t)(i0 + hi * 4 + r) * 128 + wv * 32 + ni * 16 + fr] =
            (_Float16)a2[ni][r];
  }
}

// ---------------------------------------------------------------------------
// Attention via MFMA. Block = 16 q-rows of one batch; 4 waves; grid 512.
// Zero K-rows outside sequence -> score 0 (included), matching reference.
// ---------------------------------------------------------------------------
__global__ __launch_bounds__(256) void k_attn(const _Float16* __restrict__ Qg,
                                              const _Float16* __restrict__ Kg,
                                              const _Float16* __restrict__ Vg,
                                              const float* __restrict__ Wo,
                                              const float* __restrict__ bo,
                                              float* __restrict__ outp,
                                              float* __restrict__ attwg) {
  __shared__ _Float16 Qs[16][136];
  __shared__ _Float16 Ks[80][136];
  __shared__ _Float16 Vs[96][136];
  __shared__ _Float16 Ps[16][104];
  __shared__ float sc[16][84];
  __shared__ float aw[16 * 65];
  __shared__ float wol[128][2];
  __shared__ float proj[4][16][2];
  const int tid = threadIdx.x;
  const int lane = tid & 63, wv = tid >> 6;
  const int b = blockIdx.x >> 7;
  const int i0 = (blockIdx.x & 127) << 4;
  const int rowbase = b * 2048 + i0;
  const float invscale = 0.08838834764831845f;  // 1/sqrt(128)

  {
    const int row = tid >> 4, d8 = (tid & 15) * 8;
    *(half8*)&Qs[row][d8] = *(const half8*)(Qg + (size_t)(rowbase + row) * 128 + d8);
  }
#pragma unroll
  for (int it = 0; it < 5; ++it) {
    const int idx = it * 256 + tid;
    const int lr = idx >> 4, d8 = (idx & 15) * 8;
    const int j = i0 - 32 + lr;
    half8 kv = {0, 0, 0, 0, 0, 0, 0, 0};
    if (j >= 0 && j < 2048)
      kv = *(const half8*)(Kg + (size_t)(b * 2048 + j) * 128 + d8);
    *(half8*)&Ks[lr][d8] = kv;
  }
#pragma unroll
  for (int it = 0; it < 6; ++it) {
    const int idx = it * 256 + tid;
    const int lr = idx >> 4, d8 = (idx & 15) * 8;
    const int j = i0 - 32 + lr;
    half8 vv = {0, 0, 0, 0, 0, 0, 0, 0};
    if (lr < 80 && j >= 0 && j < 2048)
      vv = *(const half8*)(Vg + (size_t)(b * 2048 + j) * 128 + d8);
    *(half8*)&Vs[lr][d8] = vv;
  }
  wol[tid >> 1][tid & 1] = Wo[tid];
  __syncthreads();

  const int fr = lane & 15, kg8 = (lane >> 4) * 8;
  // QK^T: C[16 q][80 k] = 5 col-tiles
  {
    const int nct = (wv == 0) ? 2 : 1;
    for (int p = 0; p < nct; ++p) {
      const int ct = (p == 0) ? wv : 4;
      f32x4 acc = {};
#pragma unroll
      for (int kk = 0; kk < 4; ++kk) {
        half8 a  = *(const half8*)&Qs[fr][kk * 32 + kg8];
        half8 bb = *(const half8*)&Ks[ct * 16 + fr][kk * 32 + kg8];
        acc = MFMAH(a, bb, acc);
      }
#pragma unroll
      for (int r = 0; r < 4; ++r)
        sc[(lane >> 4) * 4 + r][ct * 16 + fr] = acc[r] * invscale;
    }
  }
  __syncthreads();

  // banded softmax; wave wv owns q-rows 4wv..4wv+3
#pragma unroll 1
  for (int rr = 0; rr < 4; ++rr) {
    const int r = wv * 4 + rr;
    const int c0 = lane;
    const bool ib0 = (c0 >= r);
    const bool ib1 = (lane <= r);
    float a0 = ib0 ? sc[r][c0] : -1e30f;
    float a1 = ib1 ? sc[r][64 + lane] : -1e30f;
    float mx = fmaxf(a0, a1);
#pragma unroll
    for (int o = 1; o < 64; o <<= 1) mx = fmaxf(mx, __shfl_xor(mx, o));
    float e0 = ib0 ? __expf(a0 - mx) : 0.f;
    float e1 = ib1 ? __expf(a1 - mx) : 0.f;
    float sm = e0 + e1;
#pragma unroll
    for (int o = 1; o < 64; o <<= 1) sm += __shfl_xor(sm, o);
    const float inv = 1.0f / sm;
    const float w0 = e0 * inv, w1 = e1 * inv;
    if (ib0) aw[r * 65 + (r + 64 - c0)] = w0;
    if (ib1) aw[r * 65 + (r - lane)] = w1;
    Ps[r][c0] = (_Float16)w0;
    if (lane < 32) Ps[r][64 + lane] = (_Float16)((lane < 16) ? w1 : 0.f);
  }
  __syncthreads();

  for (int i = tid; i < 1040; i += 256)
    attwg[(size_t)rowbase * 65 + i] = aw[i];

  // PV: C2[16 q][128 d] = P(16x96) @ V(96x128)
  f32x4 c2[2] = {};
#pragma unroll
  for (int kk = 0; kk < 3; ++kk) {
    half8 a = *(const half8*)&Ps[fr][kk * 32 + kg8];
#pragma unroll
    for (int dt2 = 0; dt2 < 2; ++dt2) {
      const int d = (2 * wv + dt2) * 16 + fr;
      half8 bb;
#pragma unroll
      for (int e = 0; e < 8; ++e) bb[e] = Vs[kk * 32 + kg8 + e][d];
      c2[dt2] = MFMAH(a, bb, c2[dt2]);
    }
  }
  // projection
#pragma unroll
  for (int r = 0; r < 4; ++r) {
    float p0 = 0.f, p1 = 0.f;
#pragma unroll
    for (int dt2 = 0; dt2 < 2; ++dt2) {
      const int d = (2 * wv + dt2) * 16 + fr;
      p0 += c2[dt2][r] * wol[d][0];
      p1 += c2[dt2][r] * wol[d][1];
    }
    p0 += __shfl_xor(p0, 1); p0 += __shfl_xor(p0, 2);
    p0 += __shfl_xor(p0, 4); p0 += __shfl_xor(p0, 8);
    p1 += __shfl_xor(p1, 1); p1 += __shfl_xor(p1, 2);
    p1 += __shfl_xor(p1, 4); p1 += __shfl_xor(p1, 8);
    if (fr == 0) {
      const int q = (lane >> 4) * 4 + r;
      proj[wv][q][0] = p0;
      proj[wv][q][1] = p1;
    }
  }
  __syncthreads();
  if (tid < 16) {
    float s0 = proj[0][tid][0] + proj[1][tid][0] + proj[2][tid][0] + proj[3][tid][0];
    float s1 = proj[0][tid][1] + proj[1][tid][1] + proj[2][tid][1] + proj[3][tid][1];
    outp[((size_t)rowbase + tid) * 2 + 0] = s0 * invscale + bo[0];
    outp[((size_t)rowbase + tid) * 2 + 1] = s1 * invscale + bo[1];
  }
}

extern "C" void kernel_launch(void* const* d_in, const int* in_sizes, int n_in,
                              void* d_out, int out_size, void* d_ws, size_t ws_size,
                              hipStream_t stream) {
  const float* x  = (const float*)d_in[0];
  const float* W1 = (const float*)d_in[1];
  const float* b1 = (const float*)d_in[2];
  const float* Wq = (const float*)d_in[3];
  const float* Wk = (const float*)d_in[4];
  const float* Wv = (const float*)d_in[5];
  const float* Wo = (const float*)d_in[6];
  const float* bo = (const float*)d_in[7];
  float* out  = (float*)d_out;            // (4,2048,2)
  float* attw = out + 16384;              // (4,2048,65)

  _Float16* W1t   = (_Float16*)d_ws;            // 128x2048
  _Float16* Wqkv  = W1t + 262144;               // 3 x 128x128
  float*    PW1   = (float*)(Wqkv + 49152);     // 2048x128 f32
  float*    Hpart = PW1 + 262144;               // 8 x 8192x128 f32 (32 MB)
  _Float16* Qg    = (_Float16*)(Hpart + 8388608);  // 8192x128
  _Float16* Kg    = Qg + 1048576;
  _Float16* Vg    = Kg + 1048576;

  k_prep<<<256, 256, 0, stream>>>(W1, Wq, Wk, Wv, W1t, Wqkv);
  k_pw1<<<128, 256, 0, stream>>>(W1t, PW1);
  k_gemm1<<<512, 512, 0, stream>>>(x, W1t, Hpart);
  k_hqkv<<<512, 256, 0, stream>>>(Hpart, PW1, b1, Wqkv, Qg, Kg, Vg);
  k_attn<<<512, 256, 0, stream>>>(Qg, Kg, Vg, Wo, bo, out, attw);
}